// Round 1
// baseline (317.990 us; speedup 1.0000x reference)
//
#include <hip/hip_runtime.h>

// Problem constants: B,S,NODE,DEP,R,L,E = 32,1024,256,64,50,16,128
constexpr int B_ = 32;
constexpr int S_ = 1024;
constexpr int NODE_ = 256;
constexpr int DEP_ = 64;
constexpr int R_ = 50;
constexpr int L_ = 16;
constexpr int E_ = 128;
constexpr int FEAT_ = NODE_ + DEP_;     // 320
constexpr int NEDGE_ = B_ * E_;         // 4096 edges per layer
constexpr int BS_ = B_ * S_;            // 32768 rows
constexpr int CH_ = 16;                 // edges per relation-chunk (k_layer)
constexpr int NCH_ = 320;               // sum ceil(n_r/16) <= 306
constexpr int PREB_ = 512;              // worker blocks in k_pre
constexpr int GCH_ = 64;                // edges per GLOBAL relation-chunk (k_ctx2)
constexpr int NGC_ = 1088;              // >= 50 + 65536/64 = 1074

// ---------------------------------------------------------------------------
// Key algebra: msg = W[r][:,0:256]@ctx[t] + W[r][:,256:320]@childval[t].
// The ctx term + all index-derived metadata are layer-chain-independent ->
// precomputed in k_ctx2 (fully parallel, relation-binned ACROSS layers so
// each block runs a real 64x64x256 register-tiled GEMM). Everything is
// pre-scaled by 1/cnt[head], so accumulators A[] hold AVERAGES directly.
// Triple-buffered A: layer l scatters into A[l%3]; tail rows touched at l-1
// resolve from A[(l-1)%3] (tch flag precomputed); else persistent child[].
// k_layer(l) also (race-free, row-disjoint) copies layer l-1 rows into
// child[] and zeroes A[(l+1)%3] rows for layer l+1.
// ---------------------------------------------------------------------------
constexpr size_t N_CHILD  = (size_t)BS_ * DEP_;              // 2,097,152 floats
constexpr size_t OFF_A0   = N_CHILD;                         // A0,A1,A2 follow
constexpr size_t OFF_WT   = N_CHILD * 4;
constexpr size_t N_WT     = (size_t)R_ * FEAT_ * DEP_;       // 1,024,000
constexpr size_t OFF_SORT = OFF_WT + N_WT;
constexpr size_t N_SORT   = (size_t)L_ * NEDGE_;             // 65,536 ints
constexpr size_t OFF_CHUNK= OFF_SORT + N_SORT;
constexpr size_t N_CHUNK_I= (size_t)L_ * NCH_ * 4;           // ints
constexpr size_t OFF_HC   = OFF_CHUNK + N_CHUNK_I;
constexpr size_t N_HC     = (size_t)L_ * BS_;                // 524,288 ints
constexpr size_t OFF_MT   = OFF_HC + N_HC;                   // m_trow (tch in sign)
constexpr size_t OFF_MH   = OFF_MT + N_SORT;                 // m_hrow
constexpr size_t OFF_MI   = OFF_MH + N_SORT;                 // m_invc
constexpr size_t OFF_CD   = OFF_MI + N_SORT;                 // ctxdot
constexpr size_t N_CD     = (size_t)L_ * NEDGE_ * DEP_;      // 4,194,304
constexpr size_t OFF_GIDX = OFF_CD + N_CD;                   // global bin: pos list
constexpr size_t OFF_GCH  = OFF_GIDX + N_SORT;               // int4 * NGC_

// ---------------------------------------------------------------------------
// K_PRE: blocks 0..15 = per-layer relation binning + chunk table + head-count
// hist; blocks 16.. = W re-layout WT2[r][i4][k][c] + zero child+A0.
// ---------------------------------------------------------------------------
__global__ void k_pre(const float* __restrict__ W, const int* __restrict__ rels,
                      const int* __restrict__ heads,
                      float* __restrict__ WT2, int* __restrict__ sorted,
                      int4* __restrict__ chunks, int* __restrict__ hc,
                      float* __restrict__ zero_base) {
  int blk = blockIdx.x, tid = threadIdx.x;
  if (blk < L_) {
    int l = blk;
    __shared__ int hist[R_], startA[R_], rank[R_], cstart[R_];
    __shared__ int ntot;
    if (tid < R_) { hist[tid] = 0; rank[tid] = 0; }
    int* hcl = hc + (size_t)l * BS_;
    for (int i = tid; i < BS_; i += 256) hcl[i] = 0;
    __syncthreads();
    for (int ed = tid; ed < NEDGE_; ed += 256) {
      int b = ed >> 7, e = ed & (E_ - 1);
      atomicAdd(&hist[rels[(b * L_ + l) * E_ + e]], 1);
      atomicAdd(&hcl[b * S_ + heads[(b * L_ + l) * E_ + e]], 1);
    }
    __syncthreads();
    if (tid == 0) {
      int s = 0, cs = 0;
      for (int r = 0; r < R_; ++r) {
        startA[r] = s; s += hist[r];
        cstart[r] = cs; cs += (hist[r] + CH_ - 1) / CH_;
      }
      ntot = cs;
    }
    __syncthreads();
    for (int ed = tid; ed < NEDGE_; ed += 256) {
      int b = ed >> 7, e = ed & (E_ - 1);
      int r = rels[(b * L_ + l) * E_ + e];
      int pos = startA[r] + atomicAdd(&rank[r], 1);
      sorted[l * NEDGE_ + pos] = ed;
    }
    if (tid < R_) {
      int n = hist[tid], st = startA[tid], cs = cstart[tid];
      for (int m = 0; m * CH_ < n; ++m) {
        int c = n - m * CH_; if (c > CH_) c = CH_;
        chunks[l * NCH_ + cs + m] = make_int4(tid, st + m * CH_, c, 0);
      }
    }
    __syncthreads();
    for (int i = ntot + tid; i < NCH_; i += 256)
      chunks[l * NCH_ + i] = make_int4(0, 0, 0, 0);
  } else {
    int gtid = (blk - L_) * 256 + tid;
    const int NT = PREB_ * 256;
    for (int gid = gtid; gid < (int)N_WT; gid += NT) {
      int r = gid / 20480;           // 80*64*4
      int rem = gid - r * 20480;
      int i4 = rem >> 8;
      int k = (rem >> 2) & 63;
      int c = rem & 3;
      WT2[gid] = W[((size_t)r * DEP_ + k) * FEAT_ + 4 * i4 + c];
    }
    float4* z4 = (float4*)zero_base;          // child + A0, contiguous
    int nz4 = (int)((N_CHILD * 2) / 4);
    for (int i = gtid; i < nz4; i += NT) z4[i] = make_float4(0.f, 0.f, 0.f, 0.f);
  }
}

// ---------------------------------------------------------------------------
// K_GBIN: one block. Re-bin all L*NEDGE edge-slots by relation ACROSS layers
// (ctxdot is layer-chain-independent). Consumes the per-layer chunk tables;
// emits gidx (pos list grouped by r) + gchunks of up to GCH_=64 edges.
// ---------------------------------------------------------------------------
__global__ void k_gbin(const int4* __restrict__ chunks, int* __restrict__ gidx,
                       int4* __restrict__ gchunks) {
  __shared__ int ghist[R_], goff[R_], grank[R_], gcs[R_];
  int tid = threadIdx.x;
  if (tid < R_) { ghist[tid] = 0; grank[tid] = 0; }
  __syncthreads();
  for (int i = tid; i < L_ * NCH_; i += 1024) {
    int4 ck = chunks[i];
    if (ck.z > 0) atomicAdd(&ghist[ck.x], ck.z);
  }
  __syncthreads();
  if (tid == 0) {
    int s = 0, cs = 0;
    for (int r = 0; r < R_; ++r) {
      goff[r] = s; s += ghist[r];
      gcs[r] = cs; cs += (ghist[r] + GCH_ - 1) / GCH_;
    }
  }
  __syncthreads();
  for (int i = tid; i < L_ * NCH_; i += 1024) {
    int4 ck = chunks[i];
    if (ck.z > 0) {
      int l = i / NCH_;
      int base = atomicAdd(&grank[ck.x], ck.z);
      for (int m = 0; m < ck.z; ++m)
        gidx[goff[ck.x] + base + m] = l * NEDGE_ + ck.y + m;
    }
  }
  __syncthreads();
  if (tid < R_) {
    int n = ghist[tid], go = goff[tid], cs = gcs[tid];
    for (int m = 0; m * GCH_ < n; ++m) {
      int c = n - m * GCH_; if (c > GCH_) c = GCH_;
      gchunks[cs + m] = make_int4(tid, go + m * GCH_, c, 0);
    }
  }
  __syncthreads();
  int ntot = gcs[R_ - 1] + (ghist[R_ - 1] + GCH_ - 1) / GCH_;
  for (int i = ntot + tid; i < NGC_; i += 1024)
    gchunks[i] = make_int4(0, 0, 0, 0);
}

__device__ __forceinline__ float dot64(const float4* __restrict__ f4,
                                       const float4* __restrict__ w) {
  float a0 = 0.f, a1 = 0.f, a2 = 0.f, a3 = 0.f;
#pragma unroll
  for (int i = 0; i < 16; ++i) {
    float4 f = f4[i];
    a0 = fmaf(w[i].x, f.x, a0);
    a1 = fmaf(w[i].y, f.y, a1);
    a2 = fmaf(w[i].z, f.z, a2);
    a3 = fmaf(w[i].w, f.w, a3);
  }
  return (a0 + a1) + (a2 + a3);
}

__device__ __forceinline__ void fma4(float& a, float4 w, float4 f) {
  a = fmaf(w.x, f.x, a);
  a = fmaf(w.y, f.y, a);
  a = fmaf(w.z, f.z, a);
  a = fmaf(w.w, f.w, a);
}

// ---------------------------------------------------------------------------
// K_CTX2: register-tiled GEMM per global relation-chunk.
// Block tile: 64 outputs(k) x 64 edges(j), K-dim 256 in 4 panels of 64.
// Thread (tk=tid&15, tj=tid>>4) computes a 4x4 tile: k=4tk..+3, j=4tj..+3.
// W panel: straight float4 copy of WT2 native [i4][k] layout (no transpose);
// F panel: row-major [j][68] (pad 68 -> 2-way bank alias = free).
// Inner 4d-group: 8 ds_read_b128 per 64 FMA = 2 B LDS / FMA (balance point).
// Also writes per-slot metadata m_trow/m_hrow/m_invc (moved from old k_ctx).
// ---------------------------------------------------------------------------
__global__ void __launch_bounds__(256, 4) k_ctx2(
    const float* __restrict__ context, const float* __restrict__ WT2,
    const int* __restrict__ heads, const int* __restrict__ tails,
    const int* __restrict__ sorted, const int4* __restrict__ gchunks,
    const int* __restrict__ gidx, const int* __restrict__ hc,
    float* __restrict__ ctxdot, int* __restrict__ m_trow,
    int* __restrict__ m_hrow, float* __restrict__ m_invc) {
  int4 ck = gchunks[blockIdx.x];
  int r = ck.x, gstart = ck.y, gcnt = ck.z;
  if (gcnt == 0) return;
  int tid = threadIdx.x;
  int tk = tid & 15, tj = tid >> 4;

  __shared__ float4 Wn_s[16 * 64];                 // 16 KB, one 64-d panel of W
  __shared__ __align__(16) float F_s[GCH_][68];    // 17.4 KB gathered ctx panel
  __shared__ int   trow_s[GCH_];
  __shared__ float invc_s[GCH_];
  __shared__ int   pos_s[GCH_];

  if (tid < GCH_) {
    int jj = (tid < gcnt) ? tid : (gcnt - 1);
    int pos = gidx[gstart + jj];
    int l = pos >> 12;                             // NEDGE_ = 4096
    int ed = sorted[pos];
    int b = ed >> 7, e = ed & (E_ - 1);
    int t = tails[(b * L_ + l) * E_ + e];
    int h = heads[(b * L_ + l) * E_ + e];
    int trow = b * S_ + t, hrow = b * S_ + h;
    float invc = 1.0f / (float)hc[(size_t)l * BS_ + hrow];   // >= 1
    trow_s[tid] = trow;
    invc_s[tid] = invc;
    pos_s[tid] = pos;
    if (tid < gcnt) {
      int tch = (l > 0) && (hc[(size_t)(l - 1) * BS_ + trow] > 0);
      m_trow[pos] = trow | (tch ? (int)0x80000000 : 0);
      m_hrow[pos] = hrow;
      m_invc[pos] = invc;
    }
  }
  __syncthreads();

  float acc[4][4] = {};
  const float4* ctx4 = (const float4*)context;
  const float4* W4 = (const float4*)WT2 + (size_t)r * 80 * 64;

  int jrow = tid >> 2;        // F-staging: 4 threads per edge row
  int c0 = tid & 3;
  int trowj = trow_s[jrow];

  for (int dp = 0; dp < 4; ++dp) {
    // stage W panel: 1024 consecutive float4 (fully coalesced, no conflicts)
#pragma unroll
    for (int rep = 0; rep < 4; ++rep) {
      int idx = tid + 256 * rep;
      Wn_s[idx] = W4[1024 * dp + idx];
    }
    // stage F panel: 64 gathered rows x 64 floats; 4 lanes/row read 64B runs
#pragma unroll
    for (int rep = 0; rep < 4; ++rep) {
      int c4 = c0 + 4 * rep;
      float4 v = ctx4[(size_t)trowj * 64 + dp * 16 + c4];
      *(float4*)&F_s[jrow][4 * c4] = v;
    }
    __syncthreads();

#pragma unroll
    for (int i4 = 0; i4 < 16; ++i4) {
      float4 wv[4], fv[4];
#pragma unroll
      for (int a = 0; a < 4; ++a) wv[a] = Wn_s[i4 * 64 + 4 * tk + a];
#pragma unroll
      for (int bb = 0; bb < 4; ++bb)
        fv[bb] = *(const float4*)&F_s[4 * tj + bb][4 * i4];
#pragma unroll
      for (int a = 0; a < 4; ++a)
#pragma unroll
        for (int bb = 0; bb < 4; ++bb) fma4(acc[a][bb], wv[a], fv[bb]);
    }
    __syncthreads();
  }

  // epilogue: scale by invc[head], write 4 float4 rows (coalesced per j)
#pragma unroll
  for (int bb = 0; bb < 4; ++bb) {
    int j = 4 * tj + bb;
    if (j < gcnt) {
      float iv = invc_s[j];
      float4 o;
      o.x = acc[0][bb] * iv;
      o.y = acc[1][bb] * iv;
      o.z = acc[2][bb] * iv;
      o.w = acc[3][bb] * iv;
      ((float4*)ctxdot)[(size_t)pos_s[j] * 16 + tk] = o;
    }
  }
}

// ---------------------------------------------------------------------------
// K_LAYER: the only serial-chain kernel. Per chunk (<=16 edges, shared r):
// 4 waves; wave w handles edges j = w+4u. Gather 64-float child rows (lazy:
// A_prev if touched@l-1 else child), wave-local LDS stage, 64-wide dot,
// add precomputed ctxdot, atomic scatter of the pre-scaled contribution.
// Then: copy layer l-1 rows A_prev->child, zero A_next rows for l+1.
// ---------------------------------------------------------------------------
__global__ void __launch_bounds__(256) k_layer(
    const float* __restrict__ WT2, float* __restrict__ child,
    const int4* __restrict__ chunks, const int* __restrict__ m_trow,
    const int* __restrict__ m_hrow, const float* __restrict__ m_invc,
    const float* __restrict__ ctxdot, int l,
    const float* __restrict__ Aprev, float* __restrict__ Acur,
    float* __restrict__ Anext) {
  int tid = threadIdx.x;
  int4 ck = chunks[l * NCH_ + blockIdx.x];
  int r = ck.x, start = ck.y, ccnt = ck.z;
  __shared__ float feat[CH_][DEP_];          // 4 KB

  if (ccnt > 0) {
    int wv = tid >> 6, k = tid & 63;

    // W child-slice register cache (i4 = 64..79)
    const float4* Wp = (const float4*)WT2 + ((size_t)r * 80 + 64) * 64 + k;
    float4 w[16];
#pragma unroll
    for (int i = 0; i < 16; ++i) w[i] = Wp[(size_t)i * 64];

    int jj[4], valid[4], tch[4], trow[4], hrow[4];
    float invc[4];
#pragma unroll
    for (int u = 0; u < 4; ++u) {
      int j = wv + 4 * u;
      valid[u] = (j < ccnt);
      jj[u] = valid[u] ? j : (ccnt - 1);
      int pos = l * NEDGE_ + start + jj[u];
      int tr = m_trow[pos];
      tch[u] = (tr < 0);
      trow[u] = tr & 0x7fffffff;
      hrow[u] = m_hrow[pos];
      invc[u] = m_invc[pos];
    }

    float v[4];
#pragma unroll
    for (int u = 0; u < 4; ++u) {
      const float* p = tch[u] ? Aprev : child;   // A holds averages already
      v[u] = p[(size_t)trow[u] * DEP_ + k];
    }
#pragma unroll
    for (int u = 0; u < 4; ++u) feat[jj[u]][k] = v[u];
    __syncthreads();

#pragma unroll
    for (int u = 0; u < 4; ++u) {
      float d = dot64((const float4*)&feat[jj[u]][0], w);
      int pos = l * NEDGE_ + start + jj[u];
      float contrib = d * invc[u] + ctxdot[(size_t)pos * DEP_ + k];
      if (valid[u]) atomicAdd(&Acur[(size_t)hrow[u] * DEP_ + k], contrib);
    }
  }

  // Deferred row-disjoint phases
  int gtid = blockIdx.x * 256 + tid;
  const int NT = NCH_ * 256;
  if (l > 0) {
    const float4* Ap4 = (const float4*)Aprev;
    float4* ch4 = (float4*)child;
    const int* mh = m_hrow + (size_t)(l - 1) * NEDGE_;
    for (int idx = gtid; idx < NEDGE_ * 16; idx += NT) {
      int pos = idx >> 4, c4 = idx & 15;
      int hrow = mh[pos];
      ch4[(size_t)hrow * 16 + c4] = Ap4[(size_t)hrow * 16 + c4];
    }
  }
  if (l + 1 < L_) {
    float4* An4 = (float4*)Anext;
    const int* mh = m_hrow + (size_t)(l + 1) * NEDGE_;
    float4 z = make_float4(0.f, 0.f, 0.f, 0.f);
    for (int idx = gtid; idx < NEDGE_ * 16; idx += NT) {
      int pos = idx >> 4, c4 = idx & 15;
      An4[(size_t)mh[pos] * 16 + c4] = z;
    }
  }
}

// ---------------------------------------------------------------------------
// K_O: out = concat(context, childval); layer-15 rows read from A0 (averages).
// ---------------------------------------------------------------------------
__global__ void k_out(const float4* __restrict__ ctx4,
                      const float4* __restrict__ chd4,
                      const float4* __restrict__ A04,
                      const int* __restrict__ hc15,
                      float4* __restrict__ out4) {
  constexpr int TOT4 = B_ * S_ * (FEAT_ / 4);
  int i = blockIdx.x * blockDim.x + threadIdx.x;
  if (i >= TOT4) return;
  int row = i / 80;
  int c4 = i - row * 80;
  float4 v;
  if (c4 < 64) {
    v = ctx4[(size_t)row * 64 + c4];
  } else {
    int k4 = c4 - 64;
    v = (hc15[row] > 0) ? A04[(size_t)row * 16 + k4]
                        : chd4[(size_t)row * 16 + k4];
  }
  out4[i] = v;
}

extern "C" void kernel_launch(void* const* d_in, const int* in_sizes, int n_in,
                              void* d_out, int out_size, void* d_ws, size_t ws_size,
                              hipStream_t stream) {
  const float* context = (const float*)d_in[0];
  const float* dep_W   = (const float*)d_in[1];
  const int*   heads   = (const int*)d_in[2];
  const int*   tails   = (const int*)d_in[3];
  const int*   rels    = (const int*)d_in[4];
  float* out = (float*)d_out;

  float* ws = (float*)d_ws;
  float* child  = ws;
  float* A[3] = { ws + OFF_A0, ws + OFF_A0 + N_CHILD, ws + OFF_A0 + 2 * N_CHILD };
  float* WT2    = ws + OFF_WT;
  int*   sorted = (int*)(ws + OFF_SORT);
  int4*  chunks = (int4*)(ws + OFF_CHUNK);
  int*   hc     = (int*)(ws + OFF_HC);
  int*   m_trow = (int*)(ws + OFF_MT);
  int*   m_hrow = (int*)(ws + OFF_MH);
  float* m_invc = ws + OFF_MI;
  float* ctxdot = ws + OFF_CD;
  int*   gidx   = (int*)(ws + OFF_GIDX);
  int4*  gchunks= (int4*)(ws + OFF_GCH);

  k_pre<<<L_ + PREB_, 256, 0, stream>>>(dep_W, rels, heads, WT2, sorted,
                                        chunks, hc, child);

  k_gbin<<<1, 1024, 0, stream>>>(chunks, gidx, gchunks);

  k_ctx2<<<NGC_, 256, 0, stream>>>(context, WT2, heads, tails, sorted,
                                   gchunks, gidx, hc, ctxdot, m_trow, m_hrow,
                                   m_invc);

  for (int l = 0; l < L_; ++l) {
    float* Acur  = A[l % 3];
    float* Aprev = A[(l + 2) % 3];
    float* Anext = A[(l + 1) % 3];
    k_layer<<<NCH_, 256, 0, stream>>>(WT2, child, chunks, m_trow, m_hrow,
                                      m_invc, ctxdot, l, Aprev, Acur, Anext);
  }

  constexpr int TOT4 = B_ * S_ * (FEAT_ / 4);
  k_out<<<(TOT4 + 255) / 256, 256, 0, stream>>>(
      (const float4*)context, (const float4*)child, (const float4*)A[0],
      hc + (size_t)(L_ - 1) * BS_, (float4*)out);
}

// Round 3
// 312.107 us; speedup vs baseline: 1.0188x; 1.0188x over previous
//
#include <hip/hip_runtime.h>

// Problem constants: B,S,NODE,DEP,R,L,E = 32,1024,256,64,50,16,128
constexpr int B_ = 32;
constexpr int S_ = 1024;
constexpr int NODE_ = 256;
constexpr int DEP_ = 64;
constexpr int R_ = 50;
constexpr int L_ = 16;
constexpr int E_ = 128;
constexpr int FEAT_ = NODE_ + DEP_;     // 320
constexpr int NEDGE_ = B_ * E_;         // 4096 edges per layer
constexpr int BS_ = B_ * S_;            // 32768 rows
constexpr int CH_ = 16;                 // edges per relation-chunk (k_layer)
constexpr int NCH_ = 320;               // sum ceil(n_r/16) <= 306
constexpr int PREB_ = 512;              // worker blocks in k_pre
constexpr int GCH_ = 64;                // edges per GLOBAL relation-chunk (k_ctx2)
constexpr int NGC_ = 1088;              // >= 50 + 65536/64 = 1074

// ---------------------------------------------------------------------------
// Key algebra: msg = W[r][:,0:256]@ctx[t] + W[r][:,256:320]@childval[t].
// The ctx term + all index-derived metadata are layer-chain-independent ->
// precomputed in k_ctx2 (fully parallel, relation-binned ACROSS layers so
// each block runs a real 64x64x256 register-tiled GEMM). Everything is
// pre-scaled by 1/cnt[head], so accumulators A[] hold AVERAGES directly.
// Triple-buffered A: layer l scatters into A[l%3]; tail rows touched at l-1
// resolve from A[(l-1)%3] (tch flag precomputed); else persistent child[].
// Serial chain stays multi-launch (16x k_layer): kernel boundaries provide
// the L2-writeback ordering between plain zero/copy stores and the next
// layer's device-scope atomics (cooperative grid.sync lost that -> r2 fail).
// ---------------------------------------------------------------------------
constexpr size_t N_CHILD  = (size_t)BS_ * DEP_;              // 2,097,152 floats
constexpr size_t OFF_A0   = N_CHILD;                         // A0,A1,A2 follow
constexpr size_t OFF_WT   = N_CHILD * 4;
constexpr size_t N_WT     = (size_t)R_ * FEAT_ * DEP_;       // 1,024,000
constexpr size_t OFF_SORT = OFF_WT + N_WT;
constexpr size_t N_SORT   = (size_t)L_ * NEDGE_;             // 65,536 ints
constexpr size_t OFF_CHUNK= OFF_SORT + N_SORT;
constexpr size_t N_CHUNK_I= (size_t)L_ * NCH_ * 4;           // ints
constexpr size_t OFF_HC   = OFF_CHUNK + N_CHUNK_I;
constexpr size_t N_HC     = (size_t)L_ * BS_;                // 524,288 ints
constexpr size_t OFF_MT   = OFF_HC + N_HC;                   // m_trow (tch in sign)
constexpr size_t OFF_MH   = OFF_MT + N_SORT;                 // m_hrow
constexpr size_t OFF_MI   = OFF_MH + N_SORT;                 // m_invc
constexpr size_t OFF_CD   = OFF_MI + N_SORT;                 // ctxdot
constexpr size_t N_CD     = (size_t)L_ * NEDGE_ * DEP_;      // 4,194,304
constexpr size_t OFF_GIDX = OFF_CD + N_CD;                   // global bin: pos list
constexpr size_t OFF_GCH  = OFF_GIDX + N_SORT;               // int4 * NGC_
constexpr size_t OFF_HLR  = OFF_GCH + (size_t)NGC_ * 4;      // hist_lr [L*R] ints
constexpr size_t OFF_SLR  = OFF_HLR + (size_t)L_ * R_;       // start_lr [L*R] ints

// ---------------------------------------------------------------------------
// K_PRE: blocks 0..15 = per-layer relation binning + chunk table + head-count
// hist (also publishes hist/start tables for k_gidx); blocks 16.. = W
// re-layout WT2[r][i4][k][c] + zero child+A0.
// ---------------------------------------------------------------------------
__global__ void k_pre(const float* __restrict__ W, const int* __restrict__ rels,
                      const int* __restrict__ heads,
                      float* __restrict__ WT2, int* __restrict__ sorted,
                      int4* __restrict__ chunks, int* __restrict__ hc,
                      float* __restrict__ zero_base,
                      int* __restrict__ hist_lr, int* __restrict__ start_lr) {
  int blk = blockIdx.x, tid = threadIdx.x;
  if (blk < L_) {
    int l = blk;
    __shared__ int hist[R_], startA[R_], rank[R_], cstart[R_];
    __shared__ int ntot;
    if (tid < R_) { hist[tid] = 0; rank[tid] = 0; }
    int* hcl = hc + (size_t)l * BS_;
    for (int i = tid; i < BS_; i += 256) hcl[i] = 0;
    __syncthreads();
    for (int ed = tid; ed < NEDGE_; ed += 256) {
      int b = ed >> 7, e = ed & (E_ - 1);
      atomicAdd(&hist[rels[(b * L_ + l) * E_ + e]], 1);
      atomicAdd(&hcl[b * S_ + heads[(b * L_ + l) * E_ + e]], 1);
    }
    __syncthreads();
    if (tid == 0) {
      int s = 0, cs = 0;
      for (int r = 0; r < R_; ++r) {
        startA[r] = s; s += hist[r];
        cstart[r] = cs; cs += (hist[r] + CH_ - 1) / CH_;
      }
      ntot = cs;
    }
    __syncthreads();
    for (int ed = tid; ed < NEDGE_; ed += 256) {
      int b = ed >> 7, e = ed & (E_ - 1);
      int r = rels[(b * L_ + l) * E_ + e];
      int pos = startA[r] + atomicAdd(&rank[r], 1);
      sorted[l * NEDGE_ + pos] = ed;
    }
    if (tid < R_) {
      hist_lr[l * R_ + tid] = hist[tid];
      start_lr[l * R_ + tid] = startA[tid];
      int n = hist[tid], st = startA[tid], cs = cstart[tid];
      for (int m = 0; m * CH_ < n; ++m) {
        int c = n - m * CH_; if (c > CH_) c = CH_;
        chunks[l * NCH_ + cs + m] = make_int4(tid, st + m * CH_, c, 0);
      }
    }
    __syncthreads();
    for (int i = ntot + tid; i < NCH_; i += 256)
      chunks[l * NCH_ + i] = make_int4(0, 0, 0, 0);
  } else {
    int gtid = (blk - L_) * 256 + tid;
    const int NT = PREB_ * 256;
    for (int gid = gtid; gid < (int)N_WT; gid += NT) {
      int r = gid / 20480;           // 80*64*4
      int rem = gid - r * 20480;
      int i4 = rem >> 8;
      int k = (rem >> 2) & 63;
      int c = rem & 3;
      WT2[gid] = W[((size_t)r * DEP_ + k) * FEAT_ + 4 * i4 + c];
    }
    float4* z4 = (float4*)zero_base;          // child + A0, contiguous
    int nz4 = (int)((N_CHILD * 2) / 4);
    for (int i = gtid; i < nz4; i += NT) z4[i] = make_float4(0.f, 0.f, 0.f, 0.f);
  }
}

// ---------------------------------------------------------------------------
// K_GIDX: 800 blocks, one per (r,l) run. Each block redundantly computes the
// global r-grouped offsets from the published hist table (800 adds, trivial)
// and copies its run of `sorted` positions into gidx. Block 0 additionally
// emits the global chunk table. Replaces the serial 1-block k_gbin.
// ---------------------------------------------------------------------------
__global__ void __launch_bounds__(256) k_gidx(
    const int* __restrict__ hist_lr, const int* __restrict__ start_lr,
    int* __restrict__ gidx, int4* __restrict__ gchunks) {
  int bid = blockIdx.x;           // bid = r*L_ + l
  int r = bid / L_, l = bid - r * L_;
  int tid = threadIdx.x;
  __shared__ int sh[L_ * R_];
  __shared__ int base_s, ntot_s;
  for (int i = tid; i < L_ * R_; i += 256) sh[i] = hist_lr[i];
  __syncthreads();
  if (tid == 0) {
    int goff = 0;
    for (int rr = 0; rr < r; ++rr)
      for (int ll = 0; ll < L_; ++ll) goff += sh[ll * R_ + rr];
    for (int ll = 0; ll < l; ++ll) goff += sh[ll * R_ + r];
    base_s = goff;
  }
  __syncthreads();
  int n = sh[l * R_ + r];
  int st = start_lr[l * R_ + r];
  int base = base_s;
  for (int i = tid; i < n; i += 256)
    gidx[base + i] = l * NEDGE_ + st + i;

  if (bid == 0) {
    __shared__ int tot[R_], goffA[R_], cstart[R_];
    if (tid < R_) {
      int t = 0;
      for (int ll = 0; ll < L_; ++ll) t += sh[ll * R_ + tid];
      tot[tid] = t;
    }
    __syncthreads();
    if (tid == 0) {
      int s = 0, cs = 0;
      for (int rr = 0; rr < R_; ++rr) {
        goffA[rr] = s; s += tot[rr];
        cstart[rr] = cs; cs += (tot[rr] + GCH_ - 1) / GCH_;
      }
      ntot_s = cs;
    }
    __syncthreads();
    if (tid < R_) {
      int nn = tot[tid], go = goffA[tid], cs = cstart[tid];
      for (int m = 0; m * GCH_ < nn; ++m) {
        int c = nn - m * GCH_; if (c > GCH_) c = GCH_;
        gchunks[cs + m] = make_int4(tid, go + m * GCH_, c, 0);
      }
    }
    __syncthreads();
    for (int i = ntot_s + tid; i < NGC_; i += 256)
      gchunks[i] = make_int4(0, 0, 0, 0);
  }
}

__device__ __forceinline__ float dot64(const float4* __restrict__ f4,
                                       const float4* __restrict__ w) {
  float a0 = 0.f, a1 = 0.f, a2 = 0.f, a3 = 0.f;
#pragma unroll
  for (int i = 0; i < 16; ++i) {
    float4 f = f4[i];
    a0 = fmaf(w[i].x, f.x, a0);
    a1 = fmaf(w[i].y, f.y, a1);
    a2 = fmaf(w[i].z, f.z, a2);
    a3 = fmaf(w[i].w, f.w, a3);
  }
  return (a0 + a1) + (a2 + a3);
}

__device__ __forceinline__ void fma4(float& a, float4 w, float4 f) {
  a = fmaf(w.x, f.x, a);
  a = fmaf(w.y, f.y, a);
  a = fmaf(w.z, f.z, a);
  a = fmaf(w.w, f.w, a);
}

// ---------------------------------------------------------------------------
// K_CTX2: register-tiled GEMM per global relation-chunk.
// Block tile: 64 outputs(k) x 64 edges(j), K-dim 256 in 4 panels of 64.
// Thread (tk=tid&15, tj=tid>>4) computes a 4x4 tile with k = tk+16a (STRIDED
// -> Wn_s reads are 16 consecutive float4 across the 16 lanes = conflict-free;
// the old contiguous 4tk+a mapping was ~8-way conflicted, 13.3M cycles).
// T14 async-stage split: dp+1 W/F global loads issue right after the barrier,
// stay in flight under the FMA phase, land in LDS next iteration.
// ---------------------------------------------------------------------------
__global__ void __launch_bounds__(256, 4) k_ctx2(
    const float* __restrict__ context, const float* __restrict__ WT2,
    const int* __restrict__ heads, const int* __restrict__ tails,
    const int* __restrict__ sorted, const int4* __restrict__ gchunks,
    const int* __restrict__ gidx, const int* __restrict__ hc,
    float* __restrict__ ctxdot, int* __restrict__ m_trow,
    int* __restrict__ m_hrow, float* __restrict__ m_invc) {
  int4 ck = gchunks[blockIdx.x];
  int r = ck.x, gstart = ck.y, gcnt = ck.z;
  if (gcnt == 0) return;
  int tid = threadIdx.x;
  int tk = tid & 15, tj = tid >> 4;

  __shared__ float4 Wn_s[16 * 64];                 // 16 KB, one 64-d panel of W
  __shared__ __align__(16) float F_s[GCH_][68];    // 17.4 KB gathered ctx panel
  __shared__ int   trow_s[GCH_];
  __shared__ float invc_s[GCH_];
  __shared__ int   pos_s[GCH_];

  if (tid < GCH_) {
    int jj = (tid < gcnt) ? tid : (gcnt - 1);
    int pos = gidx[gstart + jj];
    int l = pos >> 12;                             // NEDGE_ = 4096
    int ed = sorted[pos];
    int b = ed >> 7, e = ed & (E_ - 1);
    int t = tails[(b * L_ + l) * E_ + e];
    int h = heads[(b * L_ + l) * E_ + e];
    int trow = b * S_ + t, hrow = b * S_ + h;
    float invc = 1.0f / (float)hc[(size_t)l * BS_ + hrow];   // >= 1
    trow_s[tid] = trow;
    invc_s[tid] = invc;
    pos_s[tid] = pos;
    if (tid < gcnt) {
      int tch = (l > 0) && (hc[(size_t)(l - 1) * BS_ + trow] > 0);
      m_trow[pos] = trow | (tch ? (int)0x80000000 : 0);
      m_hrow[pos] = hrow;
      m_invc[pos] = invc;
    }
  }
  __syncthreads();

  float acc[4][4] = {};
  const float4* ctx4 = (const float4*)context;
  const float4* W4 = (const float4*)WT2 + (size_t)r * 80 * 64;

  int jrow = tid >> 2;        // F-staging: 4 threads per edge row
  int c0 = tid & 3;
  int trowj = trow_s[jrow];

  float4 wreg[4], freg[4];
#pragma unroll
  for (int rep = 0; rep < 4; ++rep) {
    wreg[rep] = W4[256 * rep + tid];
    freg[rep] = ctx4[(size_t)trowj * 64 + (c0 + 4 * rep)];
  }

  for (int dp = 0; dp < 4; ++dp) {
    // land staged regs into LDS
#pragma unroll
    for (int rep = 0; rep < 4; ++rep) {
      Wn_s[256 * rep + tid] = wreg[rep];
      *(float4*)&F_s[jrow][4 * (c0 + 4 * rep)] = freg[rep];
    }
    __syncthreads();

    if (dp < 3) {   // issue next panel's loads; hidden under the FMA phase
#pragma unroll
      for (int rep = 0; rep < 4; ++rep) {
        wreg[rep] = W4[1024 * (dp + 1) + 256 * rep + tid];
        freg[rep] = ctx4[(size_t)trowj * 64 + (dp + 1) * 16 + (c0 + 4 * rep)];
      }
    }

#pragma unroll
    for (int i4 = 0; i4 < 16; ++i4) {
      float4 wv[4], fv[4];
#pragma unroll
      for (int a = 0; a < 4; ++a) wv[a] = Wn_s[i4 * 64 + tk + 16 * a];
#pragma unroll
      for (int bb = 0; bb < 4; ++bb)
        fv[bb] = *(const float4*)&F_s[4 * tj + bb][4 * i4];
#pragma unroll
      for (int a = 0; a < 4; ++a)
#pragma unroll
        for (int bb = 0; bb < 4; ++bb) fma4(acc[a][bb], wv[a], fv[bb]);
    }
    __syncthreads();
  }

  // epilogue: scale by invc[head]; k = tk+16a -> 16 dword stores, each
  // 16-lane group covers a contiguous 64B run of the row.
#pragma unroll
  for (int bb = 0; bb < 4; ++bb) {
    int j = 4 * tj + bb;
    if (j < gcnt) {
      float iv = invc_s[j];
      float* rowp = ctxdot + (size_t)pos_s[j] * DEP_;
#pragma unroll
      for (int a = 0; a < 4; ++a) rowp[tk + 16 * a] = acc[a][bb] * iv;
    }
  }
}

// ---------------------------------------------------------------------------
// K_LAYER: the only serial-chain kernel. Per chunk (<=16 edges, shared r):
// 4 waves; wave w handles edges j = w+4u. Gather 64-float child rows (lazy:
// A_prev if touched@l-1 else child), wave-local LDS stage, 64-wide dot,
// add precomputed ctxdot, atomic scatter of the pre-scaled contribution.
// Then: copy layer l-1 rows A_prev->child, zero A_next rows for l+1.
// ---------------------------------------------------------------------------
__global__ void __launch_bounds__(256) k_layer(
    const float* __restrict__ WT2, float* __restrict__ child,
    const int4* __restrict__ chunks, const int* __restrict__ m_trow,
    const int* __restrict__ m_hrow, const float* __restrict__ m_invc,
    const float* __restrict__ ctxdot, int l,
    const float* __restrict__ Aprev, float* __restrict__ Acur,
    float* __restrict__ Anext) {
  int tid = threadIdx.x;
  int4 ck = chunks[l * NCH_ + blockIdx.x];
  int r = ck.x, start = ck.y, ccnt = ck.z;
  __shared__ float feat[CH_][DEP_];          // 4 KB

  if (ccnt > 0) {
    int wv = tid >> 6, k = tid & 63;

    // W child-slice register cache (i4 = 64..79)
    const float4* Wp = (const float4*)WT2 + ((size_t)r * 80 + 64) * 64 + k;
    float4 w[16];
#pragma unroll
    for (int i = 0; i < 16; ++i) w[i] = Wp[(size_t)i * 64];

    int jj[4], valid[4], tch[4], trow[4], hrow[4];
    float invc[4];
#pragma unroll
    for (int u = 0; u < 4; ++u) {
      int j = wv + 4 * u;
      valid[u] = (j < ccnt);
      jj[u] = valid[u] ? j : (ccnt - 1);
      int pos = l * NEDGE_ + start + jj[u];
      int tr = m_trow[pos];
      tch[u] = (tr < 0);
      trow[u] = tr & 0x7fffffff;
      hrow[u] = m_hrow[pos];
      invc[u] = m_invc[pos];
    }

    float v[4];
#pragma unroll
    for (int u = 0; u < 4; ++u) {
      const float* p = tch[u] ? Aprev : child;   // A holds averages already
      v[u] = p[(size_t)trow[u] * DEP_ + k];
    }
#pragma unroll
    for (int u = 0; u < 4; ++u) feat[jj[u]][k] = v[u];
    __syncthreads();

#pragma unroll
    for (int u = 0; u < 4; ++u) {
      float d = dot64((const float4*)&feat[jj[u]][0], w);
      int pos = l * NEDGE_ + start + jj[u];
      float contrib = d * invc[u] + ctxdot[(size_t)pos * DEP_ + k];
      if (valid[u]) atomicAdd(&Acur[(size_t)hrow[u] * DEP_ + k], contrib);
    }
  }

  // Deferred row-disjoint phases
  int gtid = blockIdx.x * 256 + tid;
  const int NT = NCH_ * 256;
  if (l > 0) {
    const float4* Ap4 = (const float4*)Aprev;
    float4* ch4 = (float4*)child;
    const int* mh = m_hrow + (size_t)(l - 1) * NEDGE_;
    for (int idx = gtid; idx < NEDGE_ * 16; idx += NT) {
      int pos = idx >> 4, c4 = idx & 15;
      int hrow = mh[pos];
      ch4[(size_t)hrow * 16 + c4] = Ap4[(size_t)hrow * 16 + c4];
    }
  }
  if (l + 1 < L_) {
    float4* An4 = (float4*)Anext;
    const int* mh = m_hrow + (size_t)(l + 1) * NEDGE_;
    float4 z = make_float4(0.f, 0.f, 0.f, 0.f);
    for (int idx = gtid; idx < NEDGE_ * 16; idx += NT) {
      int pos = idx >> 4, c4 = idx & 15;
      An4[(size_t)mh[pos] * 16 + c4] = z;
    }
  }
}

// ---------------------------------------------------------------------------
// K_O: out = concat(context, childval); layer-15 rows read from A0 (averages).
// ---------------------------------------------------------------------------
__global__ void k_out(const float4* __restrict__ ctx4,
                      const float4* __restrict__ chd4,
                      const float4* __restrict__ A04,
                      const int* __restrict__ hc15,
                      float4* __restrict__ out4) {
  constexpr int TOT4 = B_ * S_ * (FEAT_ / 4);
  int i = blockIdx.x * blockDim.x + threadIdx.x;
  if (i >= TOT4) return;
  int row = i / 80;
  int c4 = i - row * 80;
  float4 v;
  if (c4 < 64) {
    v = ctx4[(size_t)row * 64 + c4];
  } else {
    int k4 = c4 - 64;
    v = (hc15[row] > 0) ? A04[(size_t)row * 16 + k4]
                        : chd4[(size_t)row * 16 + k4];
  }
  out4[i] = v;
}

extern "C" void kernel_launch(void* const* d_in, const int* in_sizes, int n_in,
                              void* d_out, int out_size, void* d_ws, size_t ws_size,
                              hipStream_t stream) {
  const float* context = (const float*)d_in[0];
  const float* dep_W   = (const float*)d_in[1];
  const int*   heads   = (const int*)d_in[2];
  const int*   tails   = (const int*)d_in[3];
  const int*   rels    = (const int*)d_in[4];
  float* out = (float*)d_out;

  float* ws = (float*)d_ws;
  float* child  = ws;
  float* A[3] = { ws + OFF_A0, ws + OFF_A0 + N_CHILD, ws + OFF_A0 + 2 * N_CHILD };
  float* WT2    = ws + OFF_WT;
  int*   sorted = (int*)(ws + OFF_SORT);
  int4*  chunks = (int4*)(ws + OFF_CHUNK);
  int*   hc     = (int*)(ws + OFF_HC);
  int*   m_trow = (int*)(ws + OFF_MT);
  int*   m_hrow = (int*)(ws + OFF_MH);
  float* m_invc = ws + OFF_MI;
  float* ctxdot = ws + OFF_CD;
  int*   gidx   = (int*)(ws + OFF_GIDX);
  int4*  gchunks= (int4*)(ws + OFF_GCH);
  int*   hist_lr= (int*)(ws + OFF_HLR);
  int*   start_lr=(int*)(ws + OFF_SLR);

  k_pre<<<L_ + PREB_, 256, 0, stream>>>(dep_W, rels, heads, WT2, sorted,
                                        chunks, hc, child, hist_lr, start_lr);

  k_gidx<<<R_ * L_, 256, 0, stream>>>(hist_lr, start_lr, gidx, gchunks);

  k_ctx2<<<NGC_, 256, 0, stream>>>(context, WT2, heads, tails, sorted,
                                   gchunks, gidx, hc, ctxdot, m_trow, m_hrow,
                                   m_invc);

  for (int l = 0; l < L_; ++l) {
    float* Acur  = A[l % 3];
    float* Aprev = A[(l + 2) % 3];
    float* Anext = A[(l + 1) % 3];
    k_layer<<<NCH_, 256, 0, stream>>>(WT2, child, chunks, m_trow, m_hrow,
                                      m_invc, ctxdot, l, Aprev, Acur, Anext);
  }

  constexpr int TOT4 = B_ * S_ * (FEAT_ / 4);
  k_out<<<(TOT4 + 255) / 256, 256, 0, stream>>>(
      (const float4*)context, (const float4*)child, (const float4*)A[0],
      hc + (size_t)(L_ - 1) * BS_, (float4*)out);
}